// Round 1
// baseline (926.564 us; speedup 1.0000x reference)
//
#include <hip/hip_runtime.h>
#include <math.h>

#define BDIM 256
constexpr int B_ = 2, H_ = 16, L_ = 1024, D_ = 64, LMAX_ = 2048;
constexpr int BH_ = B_ * H_;
constexpr float PI_F = 3.14159265358979323846f;

// ws layout (floats): a[4*L], eCr[L], eCi[L]  -> 6144 floats = 24 KB
__global__ void tables_kernel(float* __restrict__ ws) {
    float* a   = ws;
    float* eCr = ws + 4 * L_;
    float* eCi = ws + 5 * L_;
    int tid = threadIdx.x;
    int blk = blockIdx.x;
    if (blk < 4) {
        const float freqs[4] = {1.0f, 0.5f, 0.25f, 0.1f};
        float f = freqs[blk];
        float step = 2.0f * PI_F * f / (float)(LMAX_ - 1);  // linspace(0, 2*pi*f, LMAX)
        // norm over full LMAX: |p(t)|^2 = 3 + 2cos t + 2cos(t/2) + 2cos(3t/2)
        float partial = 0.0f;
        for (int j = tid; j < LMAX_; j += BDIM) {
            float t = step * (float)j;
            partial += 3.0f + 2.0f * cosf(t) + 2.0f * cosf(0.5f * t) + 2.0f * cosf(1.5f * t);
        }
        __shared__ float red[BDIM];
        red[tid] = partial;
        __syncthreads();
        for (int s = BDIM / 2; s > 0; s >>= 1) {
            if (tid < s) red[tid] += red[tid + s];
            __syncthreads();
        }
        float inv = 1.0f / sqrtf(red[0]);
        for (int l = tid; l < L_; l += BDIM) {
            float t = step * (float)l;
            float m2 = 3.0f + 2.0f * cosf(t) + 2.0f * cosf(0.5f * t) + 2.0f * cosf(1.5f * t);
            a[blk * L_ + l] = sqrtf(fmaxf(m2, 0.0f)) * inv;
        }
    } else {
        // expert: eC[l] = c * sum_k exp(i f_k t_l), t = linspace(0, 2*pi, LMAX)[:L]
        float step = 2.0f * PI_F / (float)(LMAX_ - 1);
        const float c = rsqrtf((float)LMAX_) / (sqrtf(3.0f) * sqrtf(8.0f));
        for (int l = tid; l < L_; l += BDIM) {
            float t = step * (float)l;
            float sr = 0.0f, si = 0.0f;
            for (int i = 0; i < 8; ++i) {
                float fb = 0.1f * (float)i;
                float t1 = (0.3f + fb) * t, t2 = (0.2f + fb) * t, t3 = (0.1f + fb) * t;
                sr += cosf(t1) + cosf(t2) + cosf(t3);
                si += sinf(t1) + sinf(t2) + sinf(t3);
            }
            eCr[l] = sr * c;
            eCi[l] = si * c;
        }
    }
}

// One block per (bh, 32-row q-tile). TM = 32 K/V tile. Single pass, 8 per-scale
// complex PV accumulators + per-scale denominators; divide + expert rotate at end.
__launch_bounds__(BDIM, 2)
__global__ void attn_kernel(const float* __restrict__ Qr, const float* __restrict__ Qi,
                            const float* __restrict__ Kr, const float* __restrict__ Ki,
                            const float* __restrict__ Vr, const float* __restrict__ Vi,
                            const float* __restrict__ ws, float* __restrict__ out) {
    const float* a   = ws;
    const float* eCr = ws + 4 * L_;
    const float* eCi = ws + 5 * L_;

    __shared__ float2 sQ[32][D_ + 1];  // (r,i) interleaved, padded
    __shared__ float2 sK[32][D_ + 1];
    __shared__ float2 sV[32][D_ + 1];
    __shared__ float  sE[32][32][4];   // [l][m][scale]
    __shared__ float  sDen[4][32];

    const int tid = threadIdx.x;
    const int bh  = blockIdx.x >> 5;
    const int qt  = blockIdx.x & 31;
    const int l0  = qt * 32;
    const size_t base = (size_t)bh * L_ * D_;

    // load Q tile (coalesced)
    for (int k = 0; k < 8; ++k) {
        int idx = tid + k * BDIM;          // 0..2047
        int l = idx >> 6, d = idx & 63;
        size_t g = base + (size_t)(l0 + l) * D_ + d;
        sQ[l][d] = make_float2(Qr[g], Qi[g]);
    }

    // score-phase mapping: 2x2 block per thread
    const int lp  = tid >> 4;            // 0..15
    const int jm  = tid & 15;            // 0..15
    const int lq0 = 2 * lp, lq1 = 2 * lp + 1;
    const int mq0 = 2 * jm, mq1 = 2 * jm + 1;

    float al[2][4];
#pragma unroll
    for (int s = 0; s < 4; ++s) {
        al[0][s] = a[s * L_ + l0 + lq0];
        al[1][s] = a[s * L_ + l0 + lq1];
    }

    // PV-phase mapping: lane d, 8 rows (g5 + 4r)
    const int d5 = tid & 63;
    const int g5 = tid >> 6;

    float accR[8][4], accI[8][4];
#pragma unroll
    for (int r = 0; r < 8; ++r)
#pragma unroll
        for (int s = 0; s < 4; ++s) { accR[r][s] = 0.0f; accI[r][s] = 0.0f; }
    float pden[2][4];
#pragma unroll
    for (int i = 0; i < 2; ++i)
#pragma unroll
        for (int s = 0; s < 4; ++s) pden[i][s] = 0.0f;

    for (int mt = 0; mt < 32; ++mt) {
        const int m0 = mt * 32;
        __syncthreads();  // previous iter's PV done reading sK/sV/sE
        for (int k = 0; k < 8; ++k) {
            int idx = tid + k * BDIM;
            int m = idx >> 6, d = idx & 63;
            size_t g = base + (size_t)(m0 + m) * D_ + d;
            sK[m][d] = make_float2(Kr[g], Ki[g]);
            sV[m][d] = make_float2(Vr[g], Vi[g]);
        }
        __syncthreads();

        // complex scores S0 for 2x2 block (no conjugation)
        float sr00 = 0, si00 = 0, sr01 = 0, si01 = 0;
        float sr10 = 0, si10 = 0, sr11 = 0, si11 = 0;
#pragma unroll 8
        for (int d = 0; d < D_; ++d) {
            float2 q0 = sQ[lq0][d], q1 = sQ[lq1][d];
            float2 k0 = sK[mq0][d], k1 = sK[mq1][d];
            sr00 += q0.x * k0.x - q0.y * k0.y;  si00 += q0.x * k0.y + q0.y * k0.x;
            sr01 += q0.x * k1.x - q0.y * k1.y;  si01 += q0.x * k1.y + q0.y * k1.x;
            sr10 += q1.x * k0.x - q1.y * k0.y;  si10 += q1.x * k0.y + q1.y * k0.x;
            sr11 += q1.x * k1.x - q1.y * k1.y;  si11 += q1.x * k1.y + q1.y * k1.x;
        }
        const float mag00 = sqrtf(sr00 * sr00 + si00 * si00) * 0.125f;
        const float mag01 = sqrtf(sr01 * sr01 + si01 * si01) * 0.125f;
        const float mag10 = sqrtf(sr10 * sr10 + si10 * si10) * 0.125f;
        const float mag11 = sqrtf(sr11 * sr11 + si11 * si11) * 0.125f;

#pragma unroll
        for (int s = 0; s < 4; ++s) {
            float am0 = a[s * L_ + m0 + mq0];
            float am1 = a[s * L_ + m0 + mq1];
            // logits in [0, ~0.012] -> exp without max-subtraction is safe
            float e00 = __expf(al[0][s] * am0 * mag00);
            float e01 = __expf(al[0][s] * am1 * mag01);
            float e10 = __expf(al[1][s] * am0 * mag10);
            float e11 = __expf(al[1][s] * am1 * mag11);
            sE[lq0][mq0][s] = e00; sE[lq0][mq1][s] = e01;
            sE[lq1][mq0][s] = e10; sE[lq1][mq1][s] = e11;
            pden[0][s] += e00 + e01;
            pden[1][s] += e10 + e11;
        }
        __syncthreads();

        // PV accumulate: lane d5, rows g5+4r; e reads are wave-uniform b128 broadcasts
        for (int m = 0; m < 32; ++m) {
            float2 v = sV[m][d5];
#pragma unroll
            for (int r = 0; r < 8; ++r) {
                int lr = g5 + 4 * r;
                float4 e = *(const float4*)&sE[lr][m][0];
                accR[r][0] += e.x * v.x;  accI[r][0] += e.x * v.y;
                accR[r][1] += e.y * v.x;  accI[r][1] += e.y * v.y;
                accR[r][2] += e.z * v.x;  accI[r][2] += e.z * v.y;
                accR[r][3] += e.w * v.x;  accI[r][3] += e.w * v.y;
            }
        }
    }

    // reduce denominators across the 16 lanes (jm) sharing each l-pair
#pragma unroll
    for (int i = 0; i < 2; ++i)
#pragma unroll
        for (int s = 0; s < 4; ++s) {
            float v = pden[i][s];
            v += __shfl_xor(v, 1);
            v += __shfl_xor(v, 2);
            v += __shfl_xor(v, 4);
            v += __shfl_xor(v, 8);
            pden[i][s] = v;
        }
    if (jm == 0) {
#pragma unroll
        for (int s = 0; s < 4; ++s) {
            sDen[s][lq0] = pden[0][s];
            sDen[s][lq1] = pden[1][s];
        }
    }
    __syncthreads();

    // epilogue: divide, sum scales, *0.5, expert complex rotate, store
    const float phi = 2.0f * PI_F * (float)d5 / (float)D_;
    const float cp = cosf(phi), sp = sinf(phi);
#pragma unroll
    for (int r = 0; r < 8; ++r) {
        int lr = g5 + 4 * r;
        int lg = l0 + lr;
        float resR = 0.0f, resI = 0.0f;
#pragma unroll
        for (int s = 0; s < 4; ++s) {
            float inv = 1.0f / sDen[s][lr];
            resR += accR[r][s] * inv;
            resI += accI[r][s] * inv;
        }
        resR *= 0.5f;  // 1/sqrt(num_scales)
        resI *= 0.5f;
        float Crl = eCr[lg], Cil = eCi[lg];
        float epr = cp * Crl - sp * Cil;
        float epi = sp * Crl + cp * Cil;
        float oR = resR * epr - resI * epi;
        float oI = resR * epi + resI * epr;
        size_t oidx = base + (size_t)lg * D_ + d5;
        out[oidx] = oR;
        out[oidx + (size_t)BH_ * L_ * D_] = oI;
    }
}

extern "C" void kernel_launch(void* const* d_in, const int* in_sizes, int n_in,
                              void* d_out, int out_size, void* d_ws, size_t ws_size,
                              hipStream_t stream) {
    const float* Qr = (const float*)d_in[0];
    const float* Qi = (const float*)d_in[1];
    const float* Kr = (const float*)d_in[2];
    const float* Ki = (const float*)d_in[3];
    const float* Vr = (const float*)d_in[4];
    const float* Vi = (const float*)d_in[5];
    float* ws = (float*)d_ws;
    float* out = (float*)d_out;

    tables_kernel<<<5, BDIM, 0, stream>>>(ws);
    attn_kernel<<<BH_ * 32, BDIM, 0, stream>>>(Qr, Qi, Kr, Ki, Vr, Vi, ws, out);
}

// Round 2
// 270.552 us; speedup vs baseline: 3.4247x; 3.4247x over previous
//
#include <hip/hip_runtime.h>
#include <math.h>

typedef short bf16x8 __attribute__((ext_vector_type(8)));
typedef float f32x4 __attribute__((ext_vector_type(4)));

#define BDIM 256
constexpr int B_ = 2, H_ = 16, L_ = 1024, D_ = 64, LMAX_ = 2048;
constexpr int BH_ = B_ * H_;
constexpr float PI_F = 3.14159265358979323846f;
constexpr int LDP = 72;  // padded LDS row length (bf16 elements), 144 B (16B-aligned)

// ws float layout: a[4*1024] | eCr[1024] | eCi[1024] | SVr[32*64] | SVi[32*64]  = 10240 floats

__global__ void tables_kernel(float* __restrict__ ws) {
    float* a   = ws;
    float* eCr = ws + 4 * L_;
    float* eCi = ws + 5 * L_;
    int tid = threadIdx.x;
    int blk = blockIdx.x;
    if (blk < 4) {
        const float freqs[4] = {1.0f, 0.5f, 0.25f, 0.1f};
        float f = freqs[blk];
        float step = 2.0f * PI_F * f / (float)(LMAX_ - 1);
        float partial = 0.0f;
        for (int j = tid; j < LMAX_; j += BDIM) {
            float t = step * (float)j;
            partial += 3.0f + 2.0f * cosf(t) + 2.0f * cosf(0.5f * t) + 2.0f * cosf(1.5f * t);
        }
        __shared__ float red[BDIM];
        red[tid] = partial;
        __syncthreads();
        for (int s = BDIM / 2; s > 0; s >>= 1) {
            if (tid < s) red[tid] += red[tid + s];
            __syncthreads();
        }
        float inv = 1.0f / sqrtf(red[0]);
        for (int l = tid; l < L_; l += BDIM) {
            float t = step * (float)l;
            float m2 = 3.0f + 2.0f * cosf(t) + 2.0f * cosf(0.5f * t) + 2.0f * cosf(1.5f * t);
            a[blk * L_ + l] = sqrtf(fmaxf(m2, 0.0f)) * inv;
        }
    } else {
        float step = 2.0f * PI_F / (float)(LMAX_ - 1);
        const float c = rsqrtf((float)LMAX_) / (sqrtf(3.0f) * sqrtf(8.0f));
        for (int l = tid; l < L_; l += BDIM) {
            float t = step * (float)l;
            float sr = 0.0f, si = 0.0f;
            for (int i = 0; i < 8; ++i) {
                float fb = 0.1f * (float)i;
                float t1 = (0.3f + fb) * t, t2 = (0.2f + fb) * t, t3 = (0.1f + fb) * t;
                sr += cosf(t1) + cosf(t2) + cosf(t3);
                si += sinf(t1) + sinf(t2) + sinf(t3);
            }
            eCr[l] = sr * c;
            eCi[l] = si * c;
        }
    }
}

// SV[bh][comp][d] = sum_m V[bh][m][d]  (exact fp32 rank-1 term)
__global__ void sv_kernel(const float* __restrict__ Vr, const float* __restrict__ Vi,
                          float* __restrict__ ws) {
    int blk = blockIdx.x;
    int bh = blk >> 1, comp = blk & 1;
    const float* p = (comp ? Vi : Vr) + (size_t)bh * L_ * D_;
    int d = threadIdx.x & 63;
    int ms = threadIdx.x >> 6;  // 0..3
    float s = 0.0f;
    for (int m = ms * 256; m < ms * 256 + 256; ++m) s += p[m * 64 + d];
    __shared__ float red[4][64];
    red[ms][d] = s;
    __syncthreads();
    if (ms == 0) {
        float tot = red[0][d] + red[1][d] + red[2][d] + red[3][d];
        ws[6 * L_ + comp * (BH_ * 64) + bh * 64 + d] = tot;
    }
}

__device__ __forceinline__ unsigned short f2b(float x) {
    union { float f; unsigned u; } v; v.f = x;
    return (unsigned short)((v.u + 0x8000u) >> 16);  // round-half-up bf16
}
__device__ __forceinline__ unsigned pk2(float a, float b) {
    return (unsigned)f2b(a) | ((unsigned)f2b(b) << 16);
}

#define MFMA(a, b, c) __builtin_amdgcn_mfma_f32_16x16x32_bf16((a), (b), (c), 0, 0, 0)

__launch_bounds__(BDIM, 2)
__global__ void attn_mfma_kernel(const float* __restrict__ Qr, const float* __restrict__ Qi,
                                 const float* __restrict__ Kr, const float* __restrict__ Ki,
                                 const float* __restrict__ Vr, const float* __restrict__ Vi,
                                 const float* __restrict__ ws, float* __restrict__ out) {
    __shared__ unsigned short sKr[64 * LDP], sKi[64 * LDP];
    __shared__ unsigned short sVtR[64 * LDP], sVtI[64 * LDP];  // [d][m]; doubles as Q staging
    __shared__ unsigned short sE[64 * LDP];                    // P' tile [l][m]
    __shared__ float sA[4 * 1024];                             // a-tables

    const int tid  = threadIdx.x;
    const int lane = tid & 63;
    const int w    = tid >> 6;     // wave 0..3
    const int lo16 = lane & 15;
    const int quad = lane >> 4;
    const int bh = blockIdx.x >> 4;
    const int qt = blockIdx.x & 15;
    const int l0 = qt * 64;
    const size_t base = (size_t)bh * (L_ * D_);

    // stage a-tables
    {
        const float4* src = (const float4*)ws;
        float4* dst = (float4*)sA;
        for (int i = tid; i < 1024; i += BDIM) dst[i] = src[i];
    }
    // stage Q (bf16) into sVtR/sVtI temporarily
    for (int it = 0; it < 4; ++it) {
        int g = it * BDIM + tid;           // 0..1023 float4 groups
        int r = g >> 4;
        int d4 = (g & 15) * 4;
        float4 vr = *(const float4*)(Qr + base + (size_t)(l0 + r) * D_ + d4);
        float4 vi = *(const float4*)(Qi + base + (size_t)(l0 + r) * D_ + d4);
        *(uint2*)&sVtR[r * LDP + d4] = make_uint2(pk2(vr.x, vr.y), pk2(vr.z, vr.w));
        *(uint2*)&sVtI[r * LDP + d4] = make_uint2(pk2(vi.x, vi.y), pk2(vi.z, vi.w));
    }
    __syncthreads();

    // Q fragments (register-resident for the whole kernel)
    const int qrow = w * 16 + lo16;
    bf16x8 fQr0 = *(const bf16x8*)&sVtR[qrow * LDP + quad * 8];
    bf16x8 fQr1 = *(const bf16x8*)&sVtR[qrow * LDP + 32 + quad * 8];
    bf16x8 fQi0 = *(const bf16x8*)&sVtI[qrow * LDP + quad * 8];
    bf16x8 fQi1 = *(const bf16x8*)&sVtI[qrow * LDP + 32 + quad * 8];
    bf16x8 fnQi0, fnQi1;
    {
        int4 t0 = *(int4*)&fQi0, t1 = *(int4*)&fQi1;
        t0.x ^= 0x80008000; t0.y ^= 0x80008000; t0.z ^= 0x80008000; t0.w ^= 0x80008000;
        t1.x ^= 0x80008000; t1.y ^= 0x80008000; t1.z ^= 0x80008000; t1.w ^= 0x80008000;
        *(int4*)&fnQi0 = t0; *(int4*)&fnQi1 = t1;
    }
    __syncthreads();  // done reading Q staging before sVt reuse

    // a[s][row] for this lane's 4 output rows
    float alv[16];
#pragma unroll
    for (int s = 0; s < 4; ++s)
#pragma unroll
        for (int reg = 0; reg < 4; ++reg)
            alv[reg * 4 + s] = sA[s * 1024 + l0 + w * 16 + quad * 4 + reg];

    float pden[16];
#pragma unroll
    for (int i = 0; i < 16; ++i) pden[i] = 0.0f;
    float invden[16];
#pragma unroll
    for (int i = 0; i < 16; ++i) invden[i] = 0.0f;

    f32x4 aOutR[4], aOutI[4];
#pragma unroll
    for (int dt = 0; dt < 4; ++dt) {
        aOutR[dt] = (f32x4){0.f, 0.f, 0.f, 0.f};
        aOutI[dt] = (f32x4){0.f, 0.f, 0.f, 0.f};
    }

    for (int sweep = 0; sweep < 2; ++sweep) {
        for (int mt = 0; mt < 16; ++mt) {
            const int m0 = mt * 64;
            __syncthreads();
            // stage K tile (and V tile transposed, sweep 2 only)
            for (int it = 0; it < 4; ++it) {
                int g = it * BDIM + tid;
                int r = g >> 4;
                int d4 = (g & 15) * 4;
                size_t goff = base + (size_t)(m0 + r) * D_ + d4;
                float4 kr = *(const float4*)(Kr + goff);
                float4 ki = *(const float4*)(Ki + goff);
                *(uint2*)&sKr[r * LDP + d4] = make_uint2(pk2(kr.x, kr.y), pk2(kr.z, kr.w));
                *(uint2*)&sKi[r * LDP + d4] = make_uint2(pk2(ki.x, ki.y), pk2(ki.z, ki.w));
                if (sweep) {
                    float4 wr = *(const float4*)(Vr + goff);
                    float4 wi = *(const float4*)(Vi + goff);
                    sVtR[(d4 + 0) * LDP + r] = f2b(wr.x);
                    sVtR[(d4 + 1) * LDP + r] = f2b(wr.y);
                    sVtR[(d4 + 2) * LDP + r] = f2b(wr.z);
                    sVtR[(d4 + 3) * LDP + r] = f2b(wr.w);
                    sVtI[(d4 + 0) * LDP + r] = f2b(wi.x);
                    sVtI[(d4 + 1) * LDP + r] = f2b(wi.y);
                    sVtI[(d4 + 2) * LDP + r] = f2b(wi.z);
                    sVtI[(d4 + 3) * LDP + r] = f2b(wi.w);
                }
            }
            __syncthreads();

            // scores: wave's 16 rows x 64 kv-cols, 4 col-tiles
#pragma unroll
            for (int ct = 0; ct < 4; ++ct) {
                const int colr = ct * 16 + lo16;  // kv row index in tile
                bf16x8 kr0 = *(const bf16x8*)&sKr[colr * LDP + quad * 8];
                bf16x8 kr1 = *(const bf16x8*)&sKr[colr * LDP + 32 + quad * 8];
                bf16x8 ki0 = *(const bf16x8*)&sKi[colr * LDP + quad * 8];
                bf16x8 ki1 = *(const bf16x8*)&sKi[colr * LDP + 32 + quad * 8];
                f32x4 aR = (f32x4){0.f, 0.f, 0.f, 0.f};
                f32x4 aI = (f32x4){0.f, 0.f, 0.f, 0.f};
                aR = MFMA(fQr0, kr0, aR);  aR = MFMA(fQr1, kr1, aR);
                aR = MFMA(fnQi0, ki0, aR); aR = MFMA(fnQi1, ki1, aR);   // S0r = Qr·Kr − Qi·Ki
                aI = MFMA(fQr0, ki0, aI);  aI = MFMA(fQr1, ki1, aI);
                aI = MFMA(fQi0, kr0, aI);  aI = MFMA(fQi1, kr1, aI);    // S0i = Qr·Ki + Qi·Kr
                float am0 = sA[0 * 1024 + m0 + colr];
                float am1 = sA[1 * 1024 + m0 + colr];
                float am2 = sA[2 * 1024 + m0 + colr];
                float am3 = sA[3 * 1024 + m0 + colr];
                if (sweep == 0) {
#pragma unroll
                    for (int reg = 0; reg < 4; ++reg) {
                        float sr = aR[reg], si = aI[reg];
                        float mg = sqrtf(sr * sr + si * si) * 0.125f;
                        float t0 = alv[reg * 4 + 0] * mg * am0;
                        float t1 = alv[reg * 4 + 1] * mg * am1;
                        float t2 = alv[reg * 4 + 2] * mg * am2;
                        float t3 = alv[reg * 4 + 3] * mg * am3;
                        // e^t − 1 ≈ t + t²/2  (t ≤ 0.011, err < 3e-7)
                        pden[reg * 4 + 0] += t0 * fmaf(0.5f, t0, 1.0f);
                        pden[reg * 4 + 1] += t1 * fmaf(0.5f, t1, 1.0f);
                        pden[reg * 4 + 2] += t2 * fmaf(0.5f, t2, 1.0f);
                        pden[reg * 4 + 3] += t3 * fmaf(0.5f, t3, 1.0f);
                    }
                } else {
#pragma unroll
                    for (int reg = 0; reg < 4; ++reg) {
                        float sr = aR[reg], si = aI[reg];
                        float mg = sqrtf(sr * sr + si * si) * 0.125f;
                        float t0 = alv[reg * 4 + 0] * mg * am0;
                        float t1 = alv[reg * 4 + 1] * mg * am1;
                        float t2 = alv[reg * 4 + 2] * mg * am2;
                        float t3 = alv[reg * 4 + 3] * mg * am3;
                        float pc;
                        pc = t0 * fmaf(0.5f, t0, 1.0f) * invden[reg * 4 + 0];
                        pc = fmaf(t1 * fmaf(0.5f, t1, 1.0f), invden[reg * 4 + 1], pc);
                        pc = fmaf(t2 * fmaf(0.5f, t2, 1.0f), invden[reg * 4 + 2], pc);
                        pc = fmaf(t3 * fmaf(0.5f, t3, 1.0f), invden[reg * 4 + 3], pc);
                        sE[(w * 16 + quad * 4 + reg) * LDP + colr] = f2b(pc);
                    }
                }
            }

            if (sweep) {
                // PV: out += P'·V  (single GEMM; within-wave LDS dependency only)
                bf16x8 pa0 = *(const bf16x8*)&sE[(w * 16 + lo16) * LDP + quad * 8];
                bf16x8 pa1 = *(const bf16x8*)&sE[(w * 16 + lo16) * LDP + 32 + quad * 8];
#pragma unroll
                for (int dt = 0; dt < 4; ++dt) {
                    int drow = dt * 16 + lo16;
                    bf16x8 vr0 = *(const bf16x8*)&sVtR[drow * LDP + quad * 8];
                    bf16x8 vr1 = *(const bf16x8*)&sVtR[drow * LDP + 32 + quad * 8];
                    bf16x8 vi0 = *(const bf16x8*)&sVtI[drow * LDP + quad * 8];
                    bf16x8 vi1 = *(const bf16x8*)&sVtI[drow * LDP + 32 + quad * 8];
                    aOutR[dt] = MFMA(pa0, vr0, aOutR[dt]);
                    aOutR[dt] = MFMA(pa1, vr1, aOutR[dt]);
                    aOutI[dt] = MFMA(pa0, vi0, aOutI[dt]);
                    aOutI[dt] = MFMA(pa1, vi1, aOutI[dt]);
                }
            }
        }
        if (sweep == 0) {
            // reduce den over the 16 lanes of each quad (they share rows)
#pragma unroll
            for (int i = 0; i < 16; ++i) {
                float v = pden[i];
                v += __shfl_xor(v, 1);
                v += __shfl_xor(v, 2);
                v += __shfl_xor(v, 4);
                v += __shfl_xor(v, 8);
                invden[i] = 1.0f / (1024.0f + v);   // den = L + Σ(e−1)
            }
        }
    }

    // epilogue: add c[l]·ΣV rank-1 term, scale, expert rotate, store
    float cden[4];
#pragma unroll
    for (int reg = 0; reg < 4; ++reg)
        cden[reg] = invden[reg * 4 + 0] + invden[reg * 4 + 1] +
                    invden[reg * 4 + 2] + invden[reg * 4 + 3];

    const float* eCr = ws + 4 * L_;
    const float* eCi = ws + 5 * L_;
    const float* SVr = ws + 6 * L_;
    const float* SVi = ws + 6 * L_ + BH_ * 64;
    const size_t ooff = (size_t)BH_ * L_ * D_;

#pragma unroll
    for (int dt = 0; dt < 4; ++dt) {
        int d = dt * 16 + lo16;
        float svr = SVr[bh * 64 + d];
        float svi = SVi[bh * 64 + d];
        float sp, cp;
        __sincosf((2.0f * PI_F / 64.0f) * (float)d, &sp, &cp);
#pragma unroll
        for (int reg = 0; reg < 4; ++reg) {
            int lrow = l0 + w * 16 + quad * 4 + reg;
            float numR = fmaf(cden[reg], svr, aOutR[dt][reg]) * 0.5f;
            float numI = fmaf(cden[reg], svi, aOutI[dt][reg]) * 0.5f;
            float Cr = eCr[lrow], Ci = eCi[lrow];
            float epr = cp * Cr - sp * Ci;
            float epi = sp * Cr + cp * Ci;
            size_t o = base + (size_t)lrow * D_ + d;
            out[o] = numR * epr - numI * epi;
            out[o + ooff] = numR * epi + numI * epr;
        }
    }
}

extern "C" void kernel_launch(void* const* d_in, const int* in_sizes, int n_in,
                              void* d_out, int out_size, void* d_ws, size_t ws_size,
                              hipStream_t stream) {
    const float* Qr = (const float*)d_in[0];
    const float* Qi = (const float*)d_in[1];
    const float* Kr = (const float*)d_in[2];
    const float* Ki = (const float*)d_in[3];
    const float* Vr = (const float*)d_in[4];
    const float* Vi = (const float*)d_in[5];
    float* ws = (float*)d_ws;
    float* out = (float*)d_out;

    tables_kernel<<<5, BDIM, 0, stream>>>(ws);
    sv_kernel<<<BH_ * 2, BDIM, 0, stream>>>(Vr, Vi, ws);
    attn_mfma_kernel<<<BH_ * 16, BDIM, 0, stream>>>(Qr, Qi, Kr, Ki, Vr, Vi, ws, out);
}

// Round 3
// 195.339 us; speedup vs baseline: 4.7434x; 1.3850x over previous
//
#include <hip/hip_runtime.h>
#include <math.h>

typedef short bf16x8 __attribute__((ext_vector_type(8)));
typedef float f32x4 __attribute__((ext_vector_type(4)));

#define BDIM 256
constexpr int B_ = 2, H_ = 16, L_ = 1024, D_ = 64, LMAX_ = 2048;
constexpr int BH_ = B_ * H_;
constexpr float PI_F = 3.14159265358979323846f;

// ws float layout:
//   a[4][1024]        @ 0      (fp32)
//   eCr[1024]         @ 4096
//   eCi[1024]         @ 5120
//   SVr[32][64]       @ 6144
//   SVi[32][64]       @ 8192
//   amb[16][1024]u16  @ 10240  (= a/8 bf16, rows 4-15 zero)
//   am2b[16][1024]u16 @ 18432  (= (a/8)^2 bf16, rows 4-15 zero)
//   KbR u16[2M]       @ 32768   | KbI | VtR | VtI  (each 1048576 floats)
// total = 4227072 floats ~= 16.9 MB

__device__ __forceinline__ unsigned short f2b(float x) {
    union { float f; unsigned u; } v; v.f = x;
    return (unsigned short)((v.u + 0x8000u) >> 16);
}
__device__ __forceinline__ unsigned pk2(float a, float b) {
    return (unsigned)f2b(a) | ((unsigned)f2b(b) << 16);
}

#define MFMA(a, b, c) __builtin_amdgcn_mfma_f32_16x16x32_bf16((a), (b), (c), 0, 0, 0)

__global__ void prep_kernel(const float* __restrict__ Kr, const float* __restrict__ Ki,
                            const float* __restrict__ Vr, const float* __restrict__ Vi,
                            float* __restrict__ ws) {
    const int tid = threadIdx.x;
    const int blk = blockIdx.x;
    unsigned short* KbR = (unsigned short*)(ws + 32768);
    unsigned short* KbI = KbR + 2097152;
    unsigned short* VtR = KbI + 2097152;
    unsigned short* VtI = VtR + 2097152;

    if (blk < 128) {
        // K -> bf16, same layout
        const float* src = (blk < 64) ? Kr : Ki;
        unsigned short* dst = (blk < 64) ? KbR : KbI;
        int b = blk & 63;
#pragma unroll
        for (int i = 0; i < 16; ++i) {
            size_t e = ((size_t)b * 4096 + i * 256 + tid) * 8;
            float4 x = *(const float4*)(src + e);
            float4 y = *(const float4*)(src + e + 4);
            *(uint4*)(dst + e) =
                make_uint4(pk2(x.x, x.y), pk2(x.z, x.w), pk2(y.x, y.y), pk2(y.z, y.w));
        }
    } else if (blk < 640) {
        // V -> V^T bf16 [bh][d][m]
        __shared__ unsigned short sT[64 * 68];
        int vb = blk - 128;
        int bh = vb >> 4, mt = vb & 15, m0 = mt * 64;
        for (int comp = 0; comp < 2; ++comp) {
            const float* src = (comp ? Vi : Vr) + (size_t)bh * 65536;
            unsigned short* dstA = (comp ? VtI : VtR);
#pragma unroll
            for (int i = 0; i < 4; ++i) {
                int e = i * 256 + tid;
                int m = e >> 4, d4 = (e & 15) * 4;
                float4 x = *(const float4*)(src + (size_t)(m0 + m) * 64 + d4);
                *(uint2*)&sT[m * 68 + d4] = make_uint2(pk2(x.x, x.y), pk2(x.z, x.w));
            }
            __syncthreads();
            {
                int d = tid >> 2, ms = (tid & 3) * 16;
                unsigned short v[16];
#pragma unroll
                for (int k = 0; k < 16; ++k) v[k] = sT[(ms + k) * 68 + d];
                uint4 p0 = make_uint4((unsigned)v[0] | ((unsigned)v[1] << 16),
                                      (unsigned)v[2] | ((unsigned)v[3] << 16),
                                      (unsigned)v[4] | ((unsigned)v[5] << 16),
                                      (unsigned)v[6] | ((unsigned)v[7] << 16));
                uint4 p1 = make_uint4((unsigned)v[8] | ((unsigned)v[9] << 16),
                                      (unsigned)v[10] | ((unsigned)v[11] << 16),
                                      (unsigned)v[12] | ((unsigned)v[13] << 16),
                                      (unsigned)v[14] | ((unsigned)v[15] << 16));
                unsigned short* dst = dstA + (size_t)bh * 65536 + (size_t)d * 1024 + m0 + ms;
                *(uint4*)dst = p0;
                *(uint4*)(dst + 8) = p1;
            }
            __syncthreads();
        }
    } else if (blk < 672) {
        // SV[bh][d] = sum_m V[m][d]
        int bh = blk - 640;
        __shared__ float red[4][64];
        int d = tid & 63, grp = tid >> 6;
        for (int comp = 0; comp < 2; ++comp) {
            const float* src = (comp ? Vi : Vr) + (size_t)bh * 65536;
            float s = 0.0f;
            for (int m = grp * 256; m < grp * 256 + 256; ++m) s += src[m * 64 + d];
            red[grp][d] = s;
            __syncthreads();
            if (grp == 0)
                ws[6144 + comp * 2048 + bh * 64 + d] =
                    red[0][d] + red[1][d] + red[2][d] + red[3][d];
            __syncthreads();
        }
    } else if (blk < 676) {
        // a-tables + amb/am2b rows 0-3
        int s = blk - 672;
        const float freqs[4] = {1.0f, 0.5f, 0.25f, 0.1f};
        float f = freqs[s];
        float step = 2.0f * PI_F * f / (float)(LMAX_ - 1);
        float partial = 0.0f;
        for (int j = tid; j < LMAX_; j += 256) {
            float t = step * (float)j;
            partial += 3.0f + 2.0f * cosf(t) + 2.0f * cosf(0.5f * t) + 2.0f * cosf(1.5f * t);
        }
        __shared__ float red2[256];
        red2[tid] = partial;
        __syncthreads();
        for (int st = 128; st > 0; st >>= 1) {
            if (tid < st) red2[tid] += red2[tid + st];
            __syncthreads();
        }
        float inv = 1.0f / sqrtf(red2[0]);
        unsigned short* amb = (unsigned short*)(ws + 10240);
        unsigned short* am2 = (unsigned short*)(ws + 18432);
        for (int l = tid; l < 1024; l += 256) {
            float t = step * (float)l;
            float m2 = 3.0f + 2.0f * cosf(t) + 2.0f * cosf(0.5f * t) + 2.0f * cosf(1.5f * t);
            float av = sqrtf(fmaxf(m2, 0.0f)) * inv;
            ws[s * 1024 + l] = av;
            float a8 = av * 0.125f;
            amb[s * 1024 + l] = f2b(a8);
            am2[s * 1024 + l] = f2b(a8 * a8);
        }
    } else {
        // eC tables + zero amb/am2b rows 4-15
        float step = 2.0f * PI_F / (float)(LMAX_ - 1);
        const float c = rsqrtf((float)LMAX_) / (sqrtf(3.0f) * sqrtf(8.0f));
        for (int l = tid; l < 1024; l += 256) {
            float t = step * (float)l;
            float sr = 0.0f, si = 0.0f;
            for (int i = 0; i < 8; ++i) {
                float fb = 0.1f * (float)i;
                float t1 = (0.3f + fb) * t, t2 = (0.2f + fb) * t, t3 = (0.1f + fb) * t;
                sr += cosf(t1) + cosf(t2) + cosf(t3);
                si += sinf(t1) + sinf(t2) + sinf(t3);
            }
            ws[4096 + l] = sr * c;
            ws[5120 + l] = si * c;
        }
        unsigned* ambz = (unsigned*)(ws + 10240);
        unsigned* am2z = (unsigned*)(ws + 18432);
        for (int i = tid; i < 6144; i += 256) {
            ambz[2048 + i] = 0;
            am2z[2048 + i] = 0;
        }
    }
}

// --- attn kernel helpers ---
__device__ __forceinline__ bf16x8 ldfrag(const unsigned short* b, int row, int g) {
    return *(const bf16x8*)&b[row * 64 + ((g ^ (row & 7)) << 3)];
}
__device__ __forceinline__ int seidx(int row, int col) {
    return row * 72 + ((((col >> 3) ^ (row & 7))) << 3) + (col & 7);
}
__device__ __forceinline__ bf16x8 ldfragE(const unsigned short* b, int row, int g) {
    return *(const bf16x8*)&b[row * 72 + ((g ^ (row & 7)) << 3)];
}
// stage a 64x64 bf16 tile (global, row-stride `stride` elements) into LDS, xor-swizzled
__device__ __forceinline__ void stage64s(const unsigned short* g0, int stride,
                                         unsigned short* lds, int w, int lane) {
#pragma unroll
    for (int i = 0; i < 2; ++i) {
        int c = w * 2 + i;                 // chunk 0..7 (8 rows each)
        int lrow = c * 8 + (lane >> 3);
        int lg = (lane & 7) ^ (lrow & 7);  // logical granule for this phys slot
        const unsigned short* src = g0 + (size_t)lrow * stride + lg * 8;
        __builtin_amdgcn_global_load_lds(
            (const __attribute__((address_space(1))) void*)src,
            (__attribute__((address_space(3))) void*)(lds + c * 512), 16, 0, 0);
    }
}

__launch_bounds__(BDIM, 3)
__global__ void attn2_kernel(const float* __restrict__ Qr, const float* __restrict__ Qi,
                             const float* __restrict__ ws, float* __restrict__ out) {
    __shared__ unsigned short sK0[64 * 64], sK1[64 * 64];
    __shared__ unsigned short sV0[64 * 64], sV1[64 * 64];
    __shared__ unsigned short sE[64 * 72];
    __shared__ float sDen[4][64];

    const int tid = threadIdx.x;
    const int lane = tid & 63;
    const int w = tid >> 6;
    const int lo16 = lane & 15;
    const int quad = lane >> 4;
    const int bh = blockIdx.x >> 4;
    const int qt = blockIdx.x & 15;
    const int l0 = qt * 64;
    const size_t base = (size_t)bh * (L_ * D_);

    const float* aT = ws;
    const unsigned short* ambU = (const unsigned short*)(ws + 10240);
    const unsigned short* am2U = (const unsigned short*)(ws + 18432);
    const unsigned short* KbR = (const unsigned short*)(ws + 32768);
    const unsigned short* KbI = KbR + 2097152;
    const unsigned short* VtR = KbI + 2097152;
    const unsigned short* VtI = VtR + 2097152;

    // ---- stage Q (bf16, swizzled) into sV0/sV1, pull fragments ----
#pragma unroll
    for (int it = 0; it < 2; ++it) {
        int g = it * 256 + tid;  // 0..511 granules
        int row = g >> 3, dg = g & 7;
        int phys = dg ^ (row & 7);
        const float* src = Qr + base + (size_t)(l0 + row) * 64 + dg * 8;
        float4 x = *(const float4*)src, y = *(const float4*)(src + 4);
        *(uint4*)&sV0[row * 64 + phys * 8] =
            make_uint4(pk2(x.x, x.y), pk2(x.z, x.w), pk2(y.x, y.y), pk2(y.z, y.w));
        src = Qi + base + (size_t)(l0 + row) * 64 + dg * 8;
        x = *(const float4*)src; y = *(const float4*)(src + 4);
        *(uint4*)&sV1[row * 64 + phys * 8] =
            make_uint4(pk2(x.x, x.y), pk2(x.z, x.w), pk2(y.x, y.y), pk2(y.z, y.w));
    }
    __syncthreads();
    const int qrow = w * 16 + lo16;
    bf16x8 fQr0 = ldfrag(sV0, qrow, quad);
    bf16x8 fQr1 = ldfrag(sV0, qrow, quad + 4);
    bf16x8 fQi0 = ldfrag(sV1, qrow, quad);
    bf16x8 fQi1 = ldfrag(sV1, qrow, quad + 4);
    bf16x8 fnQi0, fnQi1;
    {
        int4 t0 = *(int4*)&fQi0, t1 = *(int4*)&fQi1;
        t0.x ^= 0x80008000; t0.y ^= 0x80008000; t0.z ^= 0x80008000; t0.w ^= 0x80008000;
        t1.x ^= 0x80008000; t1.y ^= 0x80008000; t1.z ^= 0x80008000; t1.w ^= 0x80008000;
        *(int4*)&fnQi0 = t0; *(int4*)&fnQi1 = t1;
    }

    const unsigned short* gKr = KbR + (size_t)bh * 65536;
    const unsigned short* gKi = KbI + (size_t)bh * 65536;
    const unsigned short* gVr = VtR + (size_t)bh * 65536;
    const unsigned short* gVi = VtI + (size_t)bh * 65536;

    // ---- sweep 0: denominators via MFMA matvec ----
    f32x4 accM1 = (f32x4){0.f, 0.f, 0.f, 0.f};
    for (int mt = 0; mt < 16; ++mt) {
        const int m0 = mt * 64;
        __syncthreads();
        stage64s(gKr + (size_t)m0 * 64, 64, sK0, w, lane);
        stage64s(gKi + (size_t)m0 * 64, 64, sK1, w, lane);
        __syncthreads();
#pragma unroll
        for (int ct = 0; ct < 4; ++ct) {
            const int colr = ct * 16 + lo16;
            bf16x8 kr0 = ldfrag(sK0, colr, quad), kr1 = ldfrag(sK0, colr, quad + 4);
            bf16x8 ki0 = ldfrag(sK1, colr, quad), ki1 = ldfrag(sK1, colr, quad + 4);
            f32x4 aR = (f32x4){0.f, 0.f, 0.f, 0.f};
            f32x4 aI = (f32x4){0.f, 0.f, 0.f, 0.f};
            aR = MFMA(fQr0, kr0, aR);  aR = MFMA(fQr1, kr1, aR);
            aR = MFMA(fnQi0, ki0, aR); aR = MFMA(fnQi1, ki1, aR);
            aI = MFMA(fQr0, ki0, aI);  aI = MFMA(fQr1, ki1, aI);
            aI = MFMA(fQi0, kr0, aI);  aI = MFMA(fQi1, kr1, aI);
#pragma unroll
            for (int reg = 0; reg < 4; ++reg) {
                float sr = aR[reg], si = aI[reg];
                float mg = sqrtf(fmaf(sr, sr, si * si));   // |S0|
                sE[seidx(w * 16 + quad * 4 + reg, colr)] = f2b(mg);
            }
        }
        // M1 += mag @ amb   (A: own rows from sE, same-wave; B: global table rows 4-15 zero)
        bf16x8 mf0 = ldfragE(sE, w * 16 + lo16, quad);
        bf16x8 mf1 = ldfragE(sE, w * 16 + lo16, quad + 4);
        bf16x8 b0 = *(const bf16x8*)&ambU[lo16 * 1024 + m0 + quad * 8];
        bf16x8 b1 = *(const bf16x8*)&ambU[lo16 * 1024 + m0 + 32 + quad * 8];
        accM1 = MFMA(mf0, b0, accM1);
        accM1 = MFMA(mf1, b1, accM1);
    }
    // den epilogue: den_s[l] = 1024 + al_s[l]*M1[l,s]
    if (lo16 < 4) {
#pragma unroll
        for (int reg = 0; reg < 4; ++reg) {
            int r = w * 16 + quad * 4 + reg;
            float alv = aT[lo16 * 1024 + l0 + r];
            sDen[lo16][r] = 1.0f / (1024.0f + alv * accM1[reg]);
        }
    }
    __syncthreads();

    // u-fragments for rank-4 A1/A2 reconstruction (k = quad*8, slot 0)
    bf16x8 uf1 = (bf16x8){0, 0, 0, 0, 0, 0, 0, 0};
    bf16x8 uf2 = (bf16x8){0, 0, 0, 0, 0, 0, 0, 0};
    {
        float invq = sDen[quad][w * 16 + lo16];
        float alq = aT[quad * 1024 + l0 + w * 16 + lo16];
        uf1[0] = (short)f2b(invq * alq);
        uf2[0] = (short)f2b(0.5f * invq * alq * alq);
    }

    // ---- sweep 1: P' + PV ----
    f32x4 aOutR[4], aOutI[4];
#pragma unroll
    for (int dt = 0; dt < 4; ++dt) {
        aOutR[dt] = (f32x4){0.f, 0.f, 0.f, 0.f};
        aOutI[dt] = (f32x4){0.f, 0.f, 0.f, 0.f};
    }
    for (int mt = 0; mt < 16; ++mt) {
        const int m0 = mt * 64;
        __syncthreads();
        stage64s(gKr + (size_t)m0 * 64, 64, sK0, w, lane);
        stage64s(gKi + (size_t)m0 * 64, 64, sK1, w, lane);
        stage64s(gVr + m0, 1024, sV0, w, lane);
        stage64s(gVi + m0, 1024, sV1, w, lane);
        __syncthreads();
#pragma unroll
        for (int ct = 0; ct < 4; ++ct) {
            const int colr = ct * 16 + lo16;
            bf16x8 kr0 = ldfrag(sK0, colr, quad), kr1 = ldfrag(sK0, colr, quad + 4);
            bf16x8 ki0 = ldfrag(sK1, colr, quad), ki1 = ldfrag(sK1, colr, quad + 4);
            f32x4 aR = (f32x4){0.f, 0.f, 0.f, 0.f};
            f32x4 aI = (f32x4){0.f, 0.f, 0.f, 0.f};
            aR = MFMA(fQr0, kr0, aR);  aR = MFMA(fQr1, kr1, aR);
            aR = MFMA(fnQi0, ki0, aR); aR = MFMA(fnQi1, ki1, aR);
            aI = MFMA(fQr0, ki0, aI);  aI = MFMA(fQr1, ki1, aI);
            aI = MFMA(fQi0, kr0, aI);  aI = MFMA(fQi1, kr1, aI);
            // A1/A2 rank-4 tiles
            bf16x8 bf1 = (bf16x8){0, 0, 0, 0, 0, 0, 0, 0};
            bf16x8 bf2 = (bf16x8){0, 0, 0, 0, 0, 0, 0, 0};
            bf1[0] = (short)ambU[quad * 1024 + m0 + colr];
            bf2[0] = (short)am2U[quad * 1024 + m0 + colr];
            f32x4 z = (f32x4){0.f, 0.f, 0.f, 0.f};
            f32x4 a1 = MFMA(uf1, bf1, z);
            f32x4 a2 = MFMA(uf2, bf2, z);
#pragma unroll
            for (int reg = 0; reg < 4; ++reg) {
                float sr = aR[reg], si = aI[reg];
                float msq = fmaf(sr, sr, si * si);
                float mg = sqrtf(msq);
                float p = fmaf(mg, a1[reg], msq * a2[reg]);  // P' = |S0|*A1 + |S0|^2*A2
                sE[seidx(w * 16 + quad * 4 + reg, colr)] = f2b(p);
            }
        }
        // PV: out += P' @ V (A from sE same-wave rows; B from swizzled V^T tiles)
        bf16x8 pa0 = ldfragE(sE, w * 16 + lo16, quad);
        bf16x8 pa1 = ldfragE(sE, w * 16 + lo16, quad + 4);
#pragma unroll
        for (int dt = 0; dt < 4; ++dt) {
            int dr = dt * 16 + lo16;
            bf16x8 vr0 = ldfrag(sV0, dr, quad), vr1 = ldfrag(sV0, dr, quad + 4);
            bf16x8 vi0 = ldfrag(sV1, dr, quad), vi1 = ldfrag(sV1, dr, quad + 4);
            aOutR[dt] = MFMA(pa0, vr0, aOutR[dt]);
            aOutR[dt] = MFMA(pa1, vr1, aOutR[dt]);
            aOutI[dt] = MFMA(pa0, vi0, aOutI[dt]);
            aOutI[dt] = MFMA(pa1, vi1, aOutI[dt]);
        }
    }

    // ---- epilogue: rank-1 c*SumV term, scale, expert rotate, store ----
    const float* eCr = ws + 4096;
    const float* eCi = ws + 5120;
    const float* SVr = ws + 6144;
    const float* SVi = ws + 8192;
    const size_t ooff = (size_t)BH_ * L_ * D_;

    float cden[4];
#pragma unroll
    for (int reg = 0; reg < 4; ++reg) {
        int r = w * 16 + quad * 4 + reg;
        cden[reg] = sDen[0][r] + sDen[1][r] + sDen[2][r] + sDen[3][r];
    }
#pragma unroll
    for (int dt = 0; dt < 4; ++dt) {
        int d = dt * 16 + lo16;
        float svr = SVr[bh * 64 + d];
        float svi = SVi[bh * 64 + d];
        float sp, cp;
        __sincosf((2.0f * PI_F / 64.0f) * (float)d, &sp, &cp);
#pragma unroll
        for (int reg = 0; reg < 4; ++reg) {
            int lrow = l0 + w * 16 + quad * 4 + reg;
            float numR = fmaf(cden[reg], svr, aOutR[dt][reg]) * 0.5f;
            float numI = fmaf(cden[reg], svi, aOutI[dt][reg]) * 0.5f;
            float Cr = eCr[lrow], Ci = eCi[lrow];
            float epr = cp * Cr - sp * Ci;
            float epi = sp * Cr + cp * Ci;
            size_t o = base + (size_t)lrow * 64 + d;
            out[o] = numR * epr - numI * epi;
            out[o + ooff] = numR * epi + numI * epr;
        }
    }
}

extern "C" void kernel_launch(void* const* d_in, const int* in_sizes, int n_in,
                              void* d_out, int out_size, void* d_ws, size_t ws_size,
                              hipStream_t stream) {
    const float* Qr = (const float*)d_in[0];
    const float* Qi = (const float*)d_in[1];
    const float* Kr = (const float*)d_in[2];
    const float* Ki = (const float*)d_in[3];
    const float* Vr = (const float*)d_in[4];
    const float* Vi = (const float*)d_in[5];
    float* ws = (float*)d_ws;
    float* out = (float*)d_out;

    prep_kernel<<<677, BDIM, 0, stream>>>(Kr, Ki, Vr, Vi, ws);
    attn2_kernel<<<BH_ * 16, BDIM, 0, stream>>>(Qr, Qi, ws, out);
}